// Round 7
// baseline (175.027 us; speedup 1.0000x reference)
//
#include <hip/hip_runtime.h>

#define BB 8
#define FF 64
#define NN 2048
#define EPS 1e-7f
#define PTCH 4
#define BT 128                      // output tile edge
#define NT (NN / BT)                // 16 tile-cols
#define NTRI (NT * (NT + 1) / 2)    // 136 upper-tri tiles

typedef float f32x4 __attribute__((ext_vector_type(4)));  // native clang vec
                                                          // (nontemporal ok)

// ---------------------------------------------------------------------------
// Single fused kernel. Upper-triangular 128x128 tiles, 256 threads, 8x8 per
// thread.
//   * dmin fused: every block redundantly reduces min(emb[b,4,:]^2) from the
//     8 KB L2-resident f=4 row — loads issued BEFORE staging so the reduce
//     hides under staging latency; the existing __syncthreads publishes the
//     4 wave-partials. No separate pre-kernel.
//   * B-tile staged in LDS (32 KB, full 2048 float4). A-fragments read from
//     global: 16-way broadcast per wave (one 64B line), emb (4 MB) is
//     L2-resident — keeps inner loop VALU-bound (LDS 96cy < VALU 320cy per
//     CU per f-step).
//   * norms (ni/nj) accumulate in-register (+16 FMA/f/thread, hidden under
//     the 21.3 us HBM write floor); pm fragments = peeled f=4 row squared.
//   * w_ij is bitwise-symmetric (fp32 *, +, min are commutative; reference
//     gram[i][j]==gram[j][i] bitwise) => compute upper triangle only,
//     mirror-store the register transpose. Compute ~18 us < write floor.
//   * Output (134 MB) is write-once: non-temporal stores keep L2 for emb.
// ---------------------------------------------------------------------------
__global__ __launch_bounds__(256, 2) void wij_kernel(
    const float* __restrict__ emb, float* __restrict__ out) {
  __shared__ float Bs[FF][BT];  // 32 KB
  __shared__ float sm[4];

  // decode upper-triangular tile index (block-uniform scalar loop)
  int t = blockIdx.x, it = 0;
  while (t >= NT - it) { t -= NT - it; ++it; }
  const int jt = it + t;
  const int b = blockIdx.y;
  const int i0 = it * BT;
  const int j0 = jt * BT;
  const int tid = threadIdx.x;
  const int tx = tid & 15;   // col group
  const int ty = tid >> 4;   // row group

  const float* embB = emb + (size_t)b * FF * NN;

  // --- fused dmin, part 1: issue the 8 f=4-row loads first (coalesced) ---
  const float* row4 = embB + (size_t)PTCH * NN;
  float x4[8];
#pragma unroll
  for (int k = 0; k < 8; ++k) x4[k] = row4[tid + 256 * k];

  // Stage the 64x128 B-tile: 2048 float4, 8 per thread, coalesced.
#pragma unroll
  for (int r = 0; r < 8; ++r) {
    const int idx = tid + 256 * r;      // float4 index, 0..2047
    const int f = idx >> 5;             // 32 float4 per row -> f 0..63
    const int col = (idx & 31) * 4;
    *(f32x4*)&Bs[f][col] = *(const f32x4*)&embB[(size_t)f * NN + j0 + col];
  }

  // --- fused dmin, part 2: wave reduce + publish partials (pre-barrier) ---
  float pmin = 3.4e38f;
#pragma unroll
  for (int k = 0; k < 8; ++k) pmin = fminf(pmin, x4[k] * x4[k]);
#pragma unroll
  for (int off = 32; off > 0; off >>= 1)
    pmin = fminf(pmin, __shfl_down(pmin, off, 64));
  if ((tid & 63) == 0) sm[tid >> 6] = pmin;

  __syncthreads();  // covers both staging and sm[]

  const float dm = fminf(fminf(sm[0], sm[1]), fminf(sm[2], sm[3])) + EPS;
  const float inv = 1.0f / dm;

  // A-fragment base: per f read pa[f*NN] and pa[f*NN + 64] as f32x4.
  const float* pa = embB + i0 + ty * 4;

  float acc[2][2][4][4] = {};
  float ni[2][4] = {}, nj[2][4] = {};
#pragma unroll 4
  for (int f = 0; f < FF; ++f) {
    float a[2][4], bb[2][4];
    *(f32x4*)a[0] = *(const f32x4*)&pa[(size_t)f * NN];
    *(f32x4*)a[1] = *(const f32x4*)&pa[(size_t)f * NN + 64];
    *(f32x4*)bb[0] = *(const f32x4*)&Bs[f][tx * 4];
    *(f32x4*)bb[1] = *(const f32x4*)&Bs[f][64 + tx * 4];
#pragma unroll
    for (int ri = 0; ri < 2; ++ri)
#pragma unroll
      for (int m = 0; m < 4; ++m)
        ni[ri][m] = fmaf(a[ri][m], a[ri][m], ni[ri][m]);
#pragma unroll
    for (int rj = 0; rj < 2; ++rj)
#pragma unroll
      for (int n = 0; n < 4; ++n)
        nj[rj][n] = fmaf(bb[rj][n], bb[rj][n], nj[rj][n]);
#pragma unroll
    for (int ri = 0; ri < 2; ++ri)
#pragma unroll
      for (int m = 0; m < 4; ++m)
#pragma unroll
        for (int rj = 0; rj < 2; ++rj)
#pragma unroll
          for (int n = 0; n < 4; ++n)
            acc[ri][rj][m][n] = fmaf(a[ri][m], bb[rj][n], acc[ri][rj][m][n]);
  }

  // pm fragments: peeled f=4 row, squared.
  float pi[2][4], pj[2][4];
  {
    float a4[2][4], b4[2][4];
    *(f32x4*)a4[0] = *(const f32x4*)&pa[(size_t)PTCH * NN];
    *(f32x4*)a4[1] = *(const f32x4*)&pa[(size_t)PTCH * NN + 64];
    *(f32x4*)b4[0] = *(const f32x4*)&Bs[PTCH][tx * 4];
    *(f32x4*)b4[1] = *(const f32x4*)&Bs[PTCH][64 + tx * 4];
#pragma unroll
    for (int r = 0; r < 2; ++r)
#pragma unroll
      for (int k = 0; k < 4; ++k) {
        pi[r][k] = a4[r][k] * a4[r][k];
        pj[r][k] = b4[r][k] * b4[r][k];
      }
  }

  // acc -> w in place:  w = exp(-((sq*mm - dm)/dm)) = exp(1 - sq*mm*inv)
#pragma unroll
  for (int ri = 0; ri < 2; ++ri)
#pragma unroll
    for (int rj = 0; rj < 2; ++rj)
#pragma unroll
      for (int m = 0; m < 4; ++m)
#pragma unroll
        for (int n = 0; n < 4; ++n) {
          float sq = fmaf(-2.0f, acc[ri][rj][m][n], ni[ri][m] + nj[rj][n]);
          float mm = fminf(pi[ri][m], pj[rj][n]);
          acc[ri][rj][m][n] = __expf(fmaf(sq * mm, -inv, 1.0f));
        }

  float* outB = out + (size_t)b * NN * NN;

  // Normal store (non-temporal): rows i0+ri*64+ty*4+m, cols j0+rj*64+tx*4..
#pragma unroll
  for (int ri = 0; ri < 2; ++ri)
#pragma unroll
    for (int m = 0; m < 4; ++m) {
      const size_t row = (size_t)(i0 + ri * 64 + ty * 4 + m) * NN;
#pragma unroll
      for (int rj = 0; rj < 2; ++rj)
        __builtin_nontemporal_store(
            *(f32x4*)acc[ri][rj][m],
            (f32x4*)&outB[row + j0 + rj * 64 + tx * 4]);
    }

  // Mirror store (transpose, non-temporal), skipped on diagonal tiles.
  if (it != jt) {
#pragma unroll
    for (int rj = 0; rj < 2; ++rj)
#pragma unroll
      for (int n = 0; n < 4; ++n) {
        const size_t row = (size_t)(j0 + rj * 64 + tx * 4 + n) * NN;
#pragma unroll
        for (int ri = 0; ri < 2; ++ri) {
          f32x4 v;
          v.x = acc[ri][rj][0][n];
          v.y = acc[ri][rj][1][n];
          v.z = acc[ri][rj][2][n];
          v.w = acc[ri][rj][3][n];
          __builtin_nontemporal_store(
              v, (f32x4*)&outB[row + i0 + ri * 64 + ty * 4]);
        }
      }
  }
}

// ---------------------------------------------------------------------------
extern "C" void kernel_launch(void* const* d_in, const int* in_sizes, int n_in,
                              void* d_out, int out_size, void* d_ws,
                              size_t ws_size, hipStream_t stream) {
  const float* emb = (const float*)d_in[0];
  float* out = (float*)d_out;
  (void)d_ws; (void)ws_size; (void)in_sizes; (void)n_in; (void)out_size;

  wij_kernel<<<dim3(NTRI, BB), 256, 0, stream>>>(emb, out);
}

// Round 9
// 170.849 us; speedup vs baseline: 1.0245x; 1.0245x over previous
//
#include <hip/hip_runtime.h>

#define BB 8
#define FF 64
#define NN 2048
#define EPS 1e-7f
#define PTCH 4
#define BT 128                      // output tile edge
#define NT (NN / BT)                // 16 tile-cols
#define NTRI (NT * (NT + 1) / 2)    // 136 upper-tri tiles

typedef float f32x4 __attribute__((ext_vector_type(4)));  // native clang vec

// ---------------------------------------------------------------------------
// Single fused kernel. Upper-triangular 128x128 tiles, 256 threads, 8x8 per
// thread. All per-thread tile state lives in NATIVE ext_vector registers —
// no address-taken stack arrays, no reinterpret casts of locals (round-7
// suspect: SROA failure -> acc in scratch -> ~5x slowdown).
//   * fused dmin (min over emb[b,4,:]^2 + EPS), reduced per-block from the
//     L2-resident f=4 row, published via the staging barrier.
//   * B-tile in LDS (32 KB); A-fragments from global (16-way broadcast,
//     one 64B line per wave-instr, emb 4 MB = L2-resident).
//   * manual 1-deep prefetch of A/B fragments across f-iterations.
//   * norms in-register; pm = peeled f=4 fragments squared.
//   * w_ij bitwise-symmetric => upper triangle + register-transposed mirror.
//   * non-temporal stores (134 MB write-once must not evict emb from L2).
// ---------------------------------------------------------------------------
__global__ __launch_bounds__(256, 2) void wij_kernel(
    const float* __restrict__ emb, float* __restrict__ out) {
  __shared__ float Bs[FF][BT];  // 32 KB
  __shared__ float sm[4];

  // decode upper-triangular tile index (block-uniform scalar loop)
  int t = blockIdx.x, it = 0;
  while (t >= NT - it) { t -= NT - it; ++it; }
  const int jt = it + t;
  const int b = blockIdx.y;
  const int i0 = it * BT;
  const int j0 = jt * BT;
  const int tid = threadIdx.x;
  const int tx = tid & 15;   // col group
  const int ty = tid >> 4;   // row group

  const float* embB = emb + (size_t)b * FF * NN;

  // --- fused dmin, part 1: issue the 8 f=4-row loads first (coalesced) ---
  const float* row4 = embB + (size_t)PTCH * NN;
  float x0 = row4[tid], x1 = row4[tid + 256], x2 = row4[tid + 512],
        x3 = row4[tid + 768], x4 = row4[tid + 1024], x5 = row4[tid + 1280],
        x6 = row4[tid + 1536], x7 = row4[tid + 1792];

  // Stage the 64x128 B-tile: 2048 f32x4, 8 per thread, coalesced.
#pragma unroll
  for (int r = 0; r < 8; ++r) {
    const int idx = tid + 256 * r;      // f32x4 index, 0..2047
    const int f = idx >> 5;             // 32 f32x4 per row -> f 0..63
    const int col = (idx & 31) * 4;
    *(f32x4*)&Bs[f][col] = *(const f32x4*)&embB[(size_t)f * NN + j0 + col];
  }

  // --- fused dmin, part 2: wave reduce + publish partials (pre-barrier) ---
  float pmin = fminf(fminf(fminf(x0 * x0, x1 * x1), fminf(x2 * x2, x3 * x3)),
                     fminf(fminf(x4 * x4, x5 * x5), fminf(x6 * x6, x7 * x7)));
#pragma unroll
  for (int off = 32; off > 0; off >>= 1)
    pmin = fminf(pmin, __shfl_down(pmin, off, 64));
  if ((tid & 63) == 0) sm[tid >> 6] = pmin;

  __syncthreads();  // covers both staging and sm[]

  const float dm = fminf(fminf(sm[0], sm[1]), fminf(sm[2], sm[3])) + EPS;
  const float inv = 1.0f / dm;

  // A-fragment base: per f read pa[f*NN] and pa[f*NN + 64].
  const float* pa = embB + i0 + ty * 4;

  const f32x4 vzero = {0.f, 0.f, 0.f, 0.f};
  f32x4 acc[2][2][4];  // [ri][rj][m], vector lanes = n
#pragma unroll
  for (int ri = 0; ri < 2; ++ri)
#pragma unroll
    for (int rj = 0; rj < 2; ++rj)
#pragma unroll
      for (int m = 0; m < 4; ++m) acc[ri][rj][m] = vzero;
  f32x4 niv[2] = {vzero, vzero};  // lanes = m
  f32x4 njv[2] = {vzero, vzero};  // lanes = n

  // manual 1-deep prefetch across f
  f32x4 ca0 = *(const f32x4*)&pa[0];
  f32x4 ca1 = *(const f32x4*)&pa[64];
  f32x4 cb0 = *(const f32x4*)&Bs[0][tx * 4];
  f32x4 cb1 = *(const f32x4*)&Bs[0][64 + tx * 4];

#pragma unroll 4
  for (int f = 0; f < FF; ++f) {
    const f32x4 a0 = ca0, a1 = ca1, b0 = cb0, b1 = cb1;
    if (f + 1 < FF) {
      ca0 = *(const f32x4*)&pa[(size_t)(f + 1) * NN];
      ca1 = *(const f32x4*)&pa[(size_t)(f + 1) * NN + 64];
      cb0 = *(const f32x4*)&Bs[f + 1][tx * 4];
      cb1 = *(const f32x4*)&Bs[f + 1][64 + tx * 4];
    }
    niv[0] += a0 * a0;
    niv[1] += a1 * a1;
    njv[0] += b0 * b0;
    njv[1] += b1 * b1;
#pragma unroll
    for (int m = 0; m < 4; ++m) {
      acc[0][0][m] += a0[m] * b0;
      acc[0][1][m] += a0[m] * b1;
      acc[1][0][m] += a1[m] * b0;
      acc[1][1][m] += a1[m] * b1;
    }
  }

  // pm fragments: peeled f=4 row, squared.
  const f32x4 a40 = *(const f32x4*)&pa[(size_t)PTCH * NN];
  const f32x4 a41 = *(const f32x4*)&pa[(size_t)PTCH * NN + 64];
  const f32x4 b40 = *(const f32x4*)&Bs[PTCH][tx * 4];
  const f32x4 b41 = *(const f32x4*)&Bs[PTCH][64 + tx * 4];
  const f32x4 piv[2] = {a40 * a40, a41 * a41};  // lanes = m
  const f32x4 pjv[2] = {b40 * b40, b41 * b41};  // lanes = n

  // acc -> w in place:  w = exp(-((sq*mm - dm)/dm)) = exp(1 - sq*mm*inv)
#pragma unroll
  for (int ri = 0; ri < 2; ++ri)
#pragma unroll
    for (int rj = 0; rj < 2; ++rj)
#pragma unroll
      for (int m = 0; m < 4; ++m) {
        const f32x4 v = acc[ri][rj][m];
        f32x4 w;
#pragma unroll
        for (int n = 0; n < 4; ++n) {
          float sq = fmaf(-2.0f, v[n], niv[ri][m] + njv[rj][n]);
          float mm = fminf(piv[ri][m], pjv[rj][n]);
          w[n] = __expf(fmaf(sq * mm, -inv, 1.0f));
        }
        acc[ri][rj][m] = w;
      }

  float* outB = out + (size_t)b * NN * NN;

  // Normal store (non-temporal): rows i0+ri*64+ty*4+m, cols j0+rj*64+tx*4..
#pragma unroll
  for (int ri = 0; ri < 2; ++ri)
#pragma unroll
    for (int m = 0; m < 4; ++m) {
      const size_t row = (size_t)(i0 + ri * 64 + ty * 4 + m) * NN;
#pragma unroll
      for (int rj = 0; rj < 2; ++rj)
        __builtin_nontemporal_store(acc[ri][rj][m],
                                    (f32x4*)&outB[row + j0 + rj * 64 + tx * 4]);
    }

  // Mirror store (transpose, non-temporal), skipped on diagonal tiles.
  if (it != jt) {
#pragma unroll
    for (int rj = 0; rj < 2; ++rj)
#pragma unroll
      for (int n = 0; n < 4; ++n) {
        const size_t row = (size_t)(j0 + rj * 64 + tx * 4 + n) * NN;
#pragma unroll
        for (int ri = 0; ri < 2; ++ri) {
          f32x4 v = {acc[ri][rj][0][n], acc[ri][rj][1][n], acc[ri][rj][2][n],
                     acc[ri][rj][3][n]};
          __builtin_nontemporal_store(
              v, (f32x4*)&outB[row + i0 + ri * 64 + ty * 4]);
        }
      }
  }
}

// ---------------------------------------------------------------------------
extern "C" void kernel_launch(void* const* d_in, const int* in_sizes, int n_in,
                              void* d_out, int out_size, void* d_ws,
                              size_t ws_size, hipStream_t stream) {
  const float* emb = (const float*)d_in[0];
  float* out = (float*)d_out;
  (void)d_ws; (void)ws_size; (void)in_sizes; (void)n_in; (void)out_size;

  wij_kernel<<<dim3(NTRI, BB), 256, 0, stream>>>(emb, out);
}

// Round 11
// 161.486 us; speedup vs baseline: 1.0839x; 1.0580x over previous
//
#include <hip/hip_runtime.h>

#define BB 8
#define FF 64
#define NN 2048
#define EPS 1e-7f
#define PTCH 4
#define BT 128                      // output tile edge
#define NT (NN / BT)                // 16 tile-cols
#define NTRI (NT * (NT + 1) / 2)    // 136 upper-tri tiles

typedef float f32x4 __attribute__((ext_vector_type(4)));  // native clang vec

// ---------------------------------------------------------------------------
// Single fused kernel. Upper-triangular 128x128 tiles, 256 threads, 8x8 per
// thread. ROUND 10 CHANGE (untested r10, resubmitted r11): BOTH operand
// tiles staged in LDS (64 KB). The f-loop touches global memory ZERO times —
// rounds 7/9 measured ~84 us vs the 22 us VALU model, consistent with per-f
// global A-load latency (~600-900 cy L3) exposed at 2 blocks/CU; staging
// pays that latency once per block in bulk (full slack) instead of 64x on
// the critical path.
//   * A-reads: 4 distinct 16B addrs/wave, 16-lane broadcast -> conflict-free.
//   * B-reads: 2-way bank alias = free (m136).
//   * LDS/f-step/CU = 32 ds_read_b128 x 12cy = 384 cy ~ VALU 360 cy (pipes
//     overlap) -> ~22 us inner loop + staging ~1 us + epilogue.
//   * fused dmin (min over emb[b,4,:]^2 + EPS) via the staging barrier.
//   * norms in-register; pm = As/Bs[f=4] fragments squared.
//   * w_ij bitwise-symmetric => upper triangle + register-transposed mirror.
//   * non-temporal stores (134 MB write-once).
// ---------------------------------------------------------------------------
__global__ __launch_bounds__(256, 2) void wij_kernel(
    const float* __restrict__ emb, float* __restrict__ out) {
  __shared__ float As[FF][BT];  // 32 KB
  __shared__ float Bs[FF][BT];  // 32 KB
  __shared__ float sm[4];

  // decode upper-triangular tile index (block-uniform scalar loop)
  int t = blockIdx.x, it = 0;
  while (t >= NT - it) { t -= NT - it; ++it; }
  const int jt = it + t;
  const int b = blockIdx.y;
  const int i0 = it * BT;
  const int j0 = jt * BT;
  const int tid = threadIdx.x;
  const int tx = tid & 15;   // col group
  const int ty = tid >> 4;   // row group

  const float* embB = emb + (size_t)b * FF * NN;

  // --- fused dmin, part 1: issue the 8 f=4-row loads first (coalesced) ---
  const float* row4 = embB + (size_t)PTCH * NN;
  float x0 = row4[tid], x1 = row4[tid + 256], x2 = row4[tid + 512],
        x3 = row4[tid + 768], x4 = row4[tid + 1024], x5 = row4[tid + 1280],
        x6 = row4[tid + 1536], x7 = row4[tid + 1792];

  // Stage both 64x128 tiles: 2 x 2048 f32x4, 8 each per thread, coalesced.
#pragma unroll
  for (int r = 0; r < 8; ++r) {
    const int idx = tid + 256 * r;      // f32x4 index, 0..2047
    const int f = idx >> 5;             // 32 f32x4 per row -> f 0..63
    const int col = (idx & 31) * 4;
    *(f32x4*)&As[f][col] = *(const f32x4*)&embB[(size_t)f * NN + i0 + col];
    *(f32x4*)&Bs[f][col] = *(const f32x4*)&embB[(size_t)f * NN + j0 + col];
  }

  // --- fused dmin, part 2: wave reduce + publish partials (pre-barrier) ---
  float pmin = fminf(fminf(fminf(x0 * x0, x1 * x1), fminf(x2 * x2, x3 * x3)),
                     fminf(fminf(x4 * x4, x5 * x5), fminf(x6 * x6, x7 * x7)));
#pragma unroll
  for (int off = 32; off > 0; off >>= 1)
    pmin = fminf(pmin, __shfl_down(pmin, off, 64));
  if ((tid & 63) == 0) sm[tid >> 6] = pmin;

  __syncthreads();  // covers staging and sm[]

  const float dm = fminf(fminf(sm[0], sm[1]), fminf(sm[2], sm[3])) + EPS;
  const float inv = 1.0f / dm;

  const f32x4 vzero = {0.f, 0.f, 0.f, 0.f};
  f32x4 acc[2][2][4];  // [ri][rj][m], vector lanes = n
#pragma unroll
  for (int ri = 0; ri < 2; ++ri)
#pragma unroll
    for (int rj = 0; rj < 2; ++rj)
#pragma unroll
      for (int m = 0; m < 4; ++m) acc[ri][rj][m] = vzero;
  f32x4 niv[2] = {vzero, vzero};  // lanes = m
  f32x4 njv[2] = {vzero, vzero};  // lanes = n

#pragma unroll 4
  for (int f = 0; f < FF; ++f) {
    const f32x4 a0 = *(const f32x4*)&As[f][ty * 4];
    const f32x4 a1 = *(const f32x4*)&As[f][64 + ty * 4];
    const f32x4 b0 = *(const f32x4*)&Bs[f][tx * 4];
    const f32x4 b1 = *(const f32x4*)&Bs[f][64 + tx * 4];
    niv[0] += a0 * a0;
    niv[1] += a1 * a1;
    njv[0] += b0 * b0;
    njv[1] += b1 * b1;
#pragma unroll
    for (int m = 0; m < 4; ++m) {
      acc[0][0][m] += a0[m] * b0;
      acc[0][1][m] += a0[m] * b1;
      acc[1][0][m] += a1[m] * b0;
      acc[1][1][m] += a1[m] * b1;
    }
  }

  // pm fragments: f=4 rows of the LDS tiles, squared.
  const f32x4 a40 = *(const f32x4*)&As[PTCH][ty * 4];
  const f32x4 a41 = *(const f32x4*)&As[PTCH][64 + ty * 4];
  const f32x4 b40 = *(const f32x4*)&Bs[PTCH][tx * 4];
  const f32x4 b41 = *(const f32x4*)&Bs[PTCH][64 + tx * 4];
  const f32x4 piv[2] = {a40 * a40, a41 * a41};  // lanes = m
  const f32x4 pjv[2] = {b40 * b40, b41 * b41};  // lanes = n

  // acc -> w in place:  w = exp(-((sq*mm - dm)/dm)) = exp(1 - sq*mm*inv)
#pragma unroll
  for (int ri = 0; ri < 2; ++ri)
#pragma unroll
    for (int rj = 0; rj < 2; ++rj)
#pragma unroll
      for (int m = 0; m < 4; ++m) {
        const f32x4 v = acc[ri][rj][m];
        f32x4 w;
#pragma unroll
        for (int n = 0; n < 4; ++n) {
          float sq = fmaf(-2.0f, v[n], niv[ri][m] + njv[rj][n]);
          float mm = fminf(piv[ri][m], pjv[rj][n]);
          w[n] = __expf(fmaf(sq * mm, -inv, 1.0f));
        }
        acc[ri][rj][m] = w;
      }

  float* outB = out + (size_t)b * NN * NN;

  // Normal store (non-temporal): rows i0+ri*64+ty*4+m, cols j0+rj*64+tx*4..
#pragma unroll
  for (int ri = 0; ri < 2; ++ri)
#pragma unroll
    for (int m = 0; m < 4; ++m) {
      const size_t row = (size_t)(i0 + ri * 64 + ty * 4 + m) * NN;
#pragma unroll
      for (int rj = 0; rj < 2; ++rj)
        __builtin_nontemporal_store(acc[ri][rj][m],
                                    (f32x4*)&outB[row + j0 + rj * 64 + tx * 4]);
    }

  // Mirror store (transpose, non-temporal), skipped on diagonal tiles.
  if (it != jt) {
#pragma unroll
    for (int rj = 0; rj < 2; ++rj)
#pragma unroll
      for (int n = 0; n < 4; ++n) {
        const size_t row = (size_t)(j0 + rj * 64 + tx * 4 + n) * NN;
#pragma unroll
        for (int ri = 0; ri < 2; ++ri) {
          f32x4 v = {acc[ri][rj][0][n], acc[ri][rj][1][n], acc[ri][rj][2][n],
                     acc[ri][rj][3][n]};
          __builtin_nontemporal_store(
              v, (f32x4*)&outB[row + i0 + ri * 64 + ty * 4]);
        }
      }
  }
}

// ---------------------------------------------------------------------------
extern "C" void kernel_launch(void* const* d_in, const int* in_sizes, int n_in,
                              void* d_out, int out_size, void* d_ws,
                              size_t ws_size, hipStream_t stream) {
  const float* emb = (const float*)d_in[0];
  float* out = (float*)d_out;
  (void)d_ws; (void)ws_size; (void)in_sizes; (void)n_in; (void)out_size;

  wij_kernel<<<dim3(NTRI, BB), 256, 0, stream>>>(emb, out);
}